// Round 1
// baseline (2153.601 us; speedup 1.0000x reference)
//
#include <hip/hip_runtime.h>
#include <math.h>

// Problem constants
#define T_SEQ 4096
#define CDIM  768
#define NH    12
#define HD    64
#define BATCH 2
#define MROWS (BATCH * T_SEQ)   // 8192
#define N3C   (3 * CDIM)        // 2304

// Workspace layout (in floats):
//   Q: [B*H][T][HD]  at QOFF
//   K: same at KOFF, V at VOFF
//   O: [B*T][C] (attn output, proj-GEMM-ready) at OOFF
#define HEADS_TOTAL (BATCH * NH)                       // 24
#define QKV_ELEMS   ((size_t)HEADS_TOTAL * T_SEQ * HD) // 6,291,456
#define QOFF 0
#define KOFF (QKV_ELEMS)
#define VOFF (2 * QKV_ELEMS)
#define OOFF (3 * QKV_ELEMS)

// ---------------------------------------------------------------------------
// Kernel 1: qkv = x @ W_qkv + b_qkv, scattered into Q/K/V [B*H][T][HD]
// Tiled SGEMM: BM=BN=64, BK=16, 256 threads, 4x4 micro-tile per thread.
// grid = (N3C/64=36, MROWS/64=128)
// ---------------------------------------------------------------------------
__global__ __launch_bounds__(256) void qkv_gemm_kernel(
    const float* __restrict__ x, const float* __restrict__ W,
    const float* __restrict__ bias, float* __restrict__ ws) {
  __shared__ float As[16][64];   // [k][m]
  __shared__ float Bs[16][68];   // [k][n], padded

  const int t  = threadIdx.x;
  const int m0 = blockIdx.y * 64;
  const int n0 = blockIdx.x * 64;
  const int tx = t & 15, ty = t >> 4;
  const int arow = t >> 2, ak = (t & 3) << 2;       // A tile load coords
  const int brow = t >> 4, bcol = (t & 15) << 2;    // B tile load coords

  float acc[4][4] = {};

  for (int k0 = 0; k0 < CDIM; k0 += 16) {
    float4 av = *(const float4*)&x[(size_t)(m0 + arow) * CDIM + k0 + ak];
    float4 bv = *(const float4*)&W[(size_t)(k0 + brow) * N3C + n0 + bcol];
    __syncthreads();
    As[ak + 0][arow] = av.x; As[ak + 1][arow] = av.y;
    As[ak + 2][arow] = av.z; As[ak + 3][arow] = av.w;
    *(float4*)&Bs[brow][bcol] = bv;
    __syncthreads();
#pragma unroll
    for (int kk = 0; kk < 16; ++kk) {
      float4 a = *(const float4*)&As[kk][ty << 2];
      float4 b = *(const float4*)&Bs[kk][tx << 2];
      float ar[4] = {a.x, a.y, a.z, a.w};
      float br[4] = {b.x, b.y, b.z, b.w};
#pragma unroll
      for (int i = 0; i < 4; ++i)
#pragma unroll
        for (int j = 0; j < 4; ++j) acc[i][j] = fmaf(ar[i], br[j], acc[i][j]);
    }
  }

  // Epilogue: bias + scatter. Within one block n spans one (sel, h) pair.
  const int sel = n0 / CDIM;
  const int h   = (n0 % CDIM) / HD;
  float* dst = ws + (sel == 0 ? QOFF : (sel == 1 ? KOFF : VOFF));
  float4 bb = *(const float4*)&bias[n0 + (tx << 2)];
#pragma unroll
  for (int i = 0; i < 4; ++i) {
    int m = m0 + (ty << 2) + i;
    int bidx = m >> 12;          // / 4096
    int tpos = m & 4095;
    size_t base = ((size_t)(bidx * NH + h) * T_SEQ + tpos) * HD + (tx << 2);
    float4 v;
    v.x = acc[i][0] + bb.x; v.y = acc[i][1] + bb.y;
    v.z = acc[i][2] + bb.z; v.w = acc[i][3] + bb.w;
    *(float4*)&dst[base] = v;
  }
}

// ---------------------------------------------------------------------------
// Kernel 2: causal flash attention, fp32.
// grid = (T/64 = 64 q-tiles, B*H = 24), 256 threads.
// Thread t: row i = t>>2 of the Q-tile, quarter q4 = t&3.
//   - owns score/P columns j = 4*jj + q4 (jj=0..15)  [bank-conflict-free Ks reads]
//   - owns O dims d0 = q4*16 .. +15
// Q row kept in registers; K/V/P tiles in LDS; online softmax with 4-lane
// shuffle reductions (lanes 4i..4i+3 are wave-contiguous).
// O written directly in [B*T][C] layout (c = h*64 + d).
// ---------------------------------------------------------------------------
__global__ __launch_bounds__(256) void attn_kernel(
    const float* __restrict__ ws_in, float* __restrict__ Ows) {
  __shared__ float Ks[64][68];
  __shared__ float Vs[64][68];
  __shared__ float Ps[64][68];

  const int t  = threadIdx.x;
  const int qt = blockIdx.x;
  const int bh = blockIdx.y;
  const int i  = t >> 2;
  const int q4 = t & 3;
  const int d0 = q4 << 4;
  const int qrow = (qt << 6) + i;

  const float* Qb = ws_in + QOFF + (size_t)bh * T_SEQ * HD;
  const float* Kb = ws_in + KOFF + (size_t)bh * T_SEQ * HD;
  const float* Vb = ws_in + VOFF + (size_t)bh * T_SEQ * HD;

  // Q row -> registers (64 floats; 4 threads/row load redundantly, L1-served)
  float qreg[64];
#pragma unroll
  for (int kk = 0; kk < 16; ++kk) {
    float4 v = *(const float4*)&Qb[(size_t)qrow * HD + (kk << 2)];
    qreg[4 * kk + 0] = v.x; qreg[4 * kk + 1] = v.y;
    qreg[4 * kk + 2] = v.z; qreg[4 * kk + 3] = v.w;
  }

  float m_i = -INFINITY, l_i = 0.f;
  float o[16];
#pragma unroll
  for (int dd = 0; dd < 16; ++dd) o[dd] = 0.f;

  for (int kt = 0; kt <= qt; ++kt) {
    __syncthreads();  // protect Ks/Vs/Ps from previous iteration's readers
    // Cooperative, fully-coalesced K/V tile load: 64x64 floats each
#pragma unroll
    for (int ii = 0; ii < 4; ++ii) {
      int fi = ii * 1024 + t * 4;
      int j = fi >> 6, d = fi & 63;
      *(float4*)&Ks[j][d] = *(const float4*)&Kb[(size_t)(kt << 6) * HD + fi];
      *(float4*)&Vs[j][d] = *(const float4*)&Vb[(size_t)(kt << 6) * HD + fi];
    }
    __syncthreads();

    // Scores for 16 owned columns
    float s[16];
    float tmax = -INFINITY;
#pragma unroll
    for (int jj = 0; jj < 16; ++jj) {
      int j = (jj << 2) | q4;
      const float* krow = &Ks[j][0];
      float dot = 0.f;
#pragma unroll
      for (int kk = 0; kk < 16; ++kk) {
        float4 kv = *(const float4*)&krow[kk << 2];
        dot = fmaf(qreg[4 * kk + 0], kv.x, dot);
        dot = fmaf(qreg[4 * kk + 1], kv.y, dot);
        dot = fmaf(qreg[4 * kk + 2], kv.z, dot);
        dot = fmaf(qreg[4 * kk + 3], kv.w, dot);
      }
      int kcol = (kt << 6) + j;
      s[jj] = (kcol <= qrow) ? dot * 0.125f : -INFINITY;
      tmax = fmaxf(tmax, s[jj]);
    }
    // Row-wide max across the 4 lanes of this row
    tmax = fmaxf(tmax, __shfl_xor(tmax, 1));
    tmax = fmaxf(tmax, __shfl_xor(tmax, 2));
    float m_new = fmaxf(m_i, tmax);   // finite from kt=0 onward
    float alpha = __expf(m_i - m_new);

    float p[16];
    float psum = 0.f;
#pragma unroll
    for (int jj = 0; jj < 16; ++jj) {
      p[jj] = __expf(s[jj] - m_new);  // -inf -> 0
      psum += p[jj];
    }
    psum += __shfl_xor(psum, 1);
    psum += __shfl_xor(psum, 2);
    l_i = l_i * alpha + psum;
    m_i = m_new;

#pragma unroll
    for (int dd = 0; dd < 16; ++dd) o[dd] *= alpha;

    // Publish P row (scalar stores, 2-way max conflict)
#pragma unroll
    for (int jj = 0; jj < 16; ++jj) Ps[i][(jj << 2) | q4] = p[jj];
    __syncthreads();

    // PV: o[d0..d0+15] += sum_j P[i][j] * V[j][d0..]
    for (int j = 0; j < 64; ++j) {
      float pj = Ps[i][j];
      const float* vrow = &Vs[j][d0];
      float vr[16];
      *(float4*)&vr[0]  = *(const float4*)&vrow[0];
      *(float4*)&vr[4]  = *(const float4*)&vrow[4];
      *(float4*)&vr[8]  = *(const float4*)&vrow[8];
      *(float4*)&vr[12] = *(const float4*)&vrow[12];
#pragma unroll
      for (int dd = 0; dd < 16; ++dd) o[dd] = fmaf(pj, vr[dd], o[dd]);
    }
  }

  // Epilogue: normalize, write O in [B*T][C] layout (c = h*64 + d)
  float inv = 1.f / l_i;
  int b = bh / NH, h = bh % NH;
  size_t orow = ((size_t)b * T_SEQ + qrow) * CDIM + h * HD + d0;
#pragma unroll
  for (int w = 0; w < 4; ++w) {
    float4 v;
    v.x = o[4 * w + 0] * inv; v.y = o[4 * w + 1] * inv;
    v.z = o[4 * w + 2] * inv; v.w = o[4 * w + 3] * inv;
    *(float4*)&Ows[orow + 4 * w] = v;
  }
}

// ---------------------------------------------------------------------------
// Kernel 3: out = O @ W_proj + b_proj.  Same SGEMM structure.
// grid = (CDIM/64 = 12, MROWS/64 = 128)
// ---------------------------------------------------------------------------
__global__ __launch_bounds__(256) void proj_gemm_kernel(
    const float* __restrict__ A, const float* __restrict__ W,
    const float* __restrict__ bias, float* __restrict__ out) {
  __shared__ float As[16][64];
  __shared__ float Bs[16][68];

  const int t  = threadIdx.x;
  const int m0 = blockIdx.y * 64;
  const int n0 = blockIdx.x * 64;
  const int tx = t & 15, ty = t >> 4;
  const int arow = t >> 2, ak = (t & 3) << 2;
  const int brow = t >> 4, bcol = (t & 15) << 2;

  float acc[4][4] = {};

  for (int k0 = 0; k0 < CDIM; k0 += 16) {
    float4 av = *(const float4*)&A[(size_t)(m0 + arow) * CDIM + k0 + ak];
    float4 bv = *(const float4*)&W[(size_t)(k0 + brow) * CDIM + n0 + bcol];
    __syncthreads();
    As[ak + 0][arow] = av.x; As[ak + 1][arow] = av.y;
    As[ak + 2][arow] = av.z; As[ak + 3][arow] = av.w;
    *(float4*)&Bs[brow][bcol] = bv;
    __syncthreads();
#pragma unroll
    for (int kk = 0; kk < 16; ++kk) {
      float4 a = *(const float4*)&As[kk][ty << 2];
      float4 b = *(const float4*)&Bs[kk][tx << 2];
      float ar[4] = {a.x, a.y, a.z, a.w};
      float br[4] = {b.x, b.y, b.z, b.w};
#pragma unroll
      for (int i = 0; i < 4; ++i)
#pragma unroll
        for (int j = 0; j < 4; ++j) acc[i][j] = fmaf(ar[i], br[j], acc[i][j]);
    }
  }

  float4 bb = *(const float4*)&bias[n0 + (tx << 2)];
#pragma unroll
  for (int i = 0; i < 4; ++i) {
    int m = m0 + (ty << 2) + i;
    float4 v;
    v.x = acc[i][0] + bb.x; v.y = acc[i][1] + bb.y;
    v.z = acc[i][2] + bb.z; v.w = acc[i][3] + bb.w;
    *(float4*)&out[(size_t)m * CDIM + n0 + (tx << 2)] = v;
  }
}

// ---------------------------------------------------------------------------
extern "C" void kernel_launch(void* const* d_in, const int* in_sizes, int n_in,
                              void* d_out, int out_size, void* d_ws, size_t ws_size,
                              hipStream_t stream) {
  (void)in_sizes; (void)n_in; (void)out_size; (void)ws_size;
  const float* x      = (const float*)d_in[0];
  const float* W_qkv  = (const float*)d_in[1];
  const float* b_qkv  = (const float*)d_in[2];
  const float* W_proj = (const float*)d_in[3];
  const float* b_proj = (const float*)d_in[4];
  float* out = (float*)d_out;
  float* ws  = (float*)d_ws;

  // 1) QKV projection (+bias), scattered to [B*H][T][HD]
  qkv_gemm_kernel<<<dim3(N3C / 64, MROWS / 64), 256, 0, stream>>>(
      x, W_qkv, b_qkv, ws);

  // 2) Causal flash attention -> O in [B*T][C]
  attn_kernel<<<dim3(T_SEQ / 64, HEADS_TOTAL), 256, 0, stream>>>(
      ws, ws + OOFF);

  // 3) Output projection (+bias)
  proj_gemm_kernel<<<dim3(CDIM / 64, MROWS / 64), 256, 0, stream>>>(
      ws + OOFF, W_proj, b_proj, out);
}

// Round 2
// 1212.650 us; speedup vs baseline: 1.7759x; 1.7759x over previous
//
#include <hip/hip_runtime.h>
#include <math.h>

// Problem constants
#define T_SEQ 4096
#define CDIM  768
#define NH    12
#define HD    64
#define BATCH 2
#define MROWS (BATCH * T_SEQ)   // 8192
#define N3C   (3 * CDIM)        // 2304
#define HEADS_TOTAL (BATCH * NH)                       // 24
#define QKV_ELEMS   ((size_t)HEADS_TOTAL * T_SEQ * HD) // 6,291,456

typedef __bf16 bf16x8 __attribute__((ext_vector_type(8)));
typedef __bf16 bf16x4 __attribute__((ext_vector_type(4)));
typedef __bf16 bf16x2 __attribute__((ext_vector_type(2)));
typedef float  f32x4  __attribute__((ext_vector_type(4)));

// Workspace layout:
//   Qw  bf16 [B*H][T][64]   (pre-scaled by 0.125)
//   Kw  bf16 [B*H][T][64]
//   Vtw bf16 [B*H][64][T]   (transposed: PV B-op... A-op contiguity)
//   Ow  f32  [B*T][C]       (attn output, proj-ready)

// ---------------------------------------------------------------------------
// Kernel 1: qkv = x @ W_qkv + b_qkv  (fp32 SGEMM), epilogue converts to bf16
// and scatters: Q (x0.125) / K -> [bh][T][64], V -> transposed [bh][64][T].
// grid = (N3C/64=36, MROWS/64=128), 256 threads.
// ---------------------------------------------------------------------------
__global__ __launch_bounds__(256) void qkv_gemm_kernel(
    const float* __restrict__ x, const float* __restrict__ W,
    const float* __restrict__ bias, __bf16* __restrict__ Qw,
    __bf16* __restrict__ Kw, __bf16* __restrict__ Vtw) {
  __shared__ float As[16][64];   // [k][m]
  __shared__ float Bs[16][68];   // [k][n], padded

  const int t  = threadIdx.x;
  const int m0 = blockIdx.y * 64;
  const int n0 = blockIdx.x * 64;
  const int tx = t & 15, ty = t >> 4;
  const int arow = t >> 2, ak = (t & 3) << 2;
  const int brow = t >> 4, bcol = (t & 15) << 2;

  float acc[4][4] = {};

  for (int k0 = 0; k0 < CDIM; k0 += 16) {
    float4 av = *(const float4*)&x[(size_t)(m0 + arow) * CDIM + k0 + ak];
    float4 bv = *(const float4*)&W[(size_t)(k0 + brow) * N3C + n0 + bcol];
    __syncthreads();
    As[ak + 0][arow] = av.x; As[ak + 1][arow] = av.y;
    As[ak + 2][arow] = av.z; As[ak + 3][arow] = av.w;
    *(float4*)&Bs[brow][bcol] = bv;
    __syncthreads();
#pragma unroll
    for (int kk = 0; kk < 16; ++kk) {
      float4 a = *(const float4*)&As[kk][ty << 2];
      float4 b = *(const float4*)&Bs[kk][tx << 2];
      float ar[4] = {a.x, a.y, a.z, a.w};
      float br[4] = {b.x, b.y, b.z, b.w};
#pragma unroll
      for (int i = 0; i < 4; ++i)
#pragma unroll
        for (int j = 0; j < 4; ++j) acc[i][j] = fmaf(ar[i], br[j], acc[i][j]);
    }
  }

  // Epilogue: bias, cvt bf16, scatter. n0 spans exactly one (sel, head, d-quad).
  const int sel = n0 / CDIM;
  const int hh  = (n0 % CDIM) / HD;
  const int d0  = tx << 2;               // n0 % 64 == 0, so d = d0 + j
  float4 bb = *(const float4*)&bias[n0 + d0];
  float bj[4] = {bb.x, bb.y, bb.z, bb.w};

  if (sel < 2) {
    __bf16* dst = (sel == 0) ? Qw : Kw;
    const float scl = (sel == 0) ? 0.125f : 1.0f;   // fold 1/sqrt(D) into Q
#pragma unroll
    for (int i = 0; i < 4; ++i) {
      int m = m0 + (ty << 2) + i;
      int b = m >> 12, tp = m & 4095;
      int bh = b * NH + hh;
      bf16x4 v;
      v[0] = (__bf16)((acc[i][0] + bj[0]) * scl);
      v[1] = (__bf16)((acc[i][1] + bj[1]) * scl);
      v[2] = (__bf16)((acc[i][2] + bj[2]) * scl);
      v[3] = (__bf16)((acc[i][3] + bj[3]) * scl);
      *(bf16x4*)&dst[((size_t)bh * T_SEQ + tp) * HD + d0] = v;
    }
  } else {
    int m = m0 + (ty << 2);
    int b = m >> 12, tp = m & 4095;      // 4 consecutive t, same batch
    int bh = b * NH + hh;
#pragma unroll
    for (int j = 0; j < 4; ++j) {
      bf16x4 v;
      v[0] = (__bf16)(acc[0][j] + bj[j]);
      v[1] = (__bf16)(acc[1][j] + bj[j]);
      v[2] = (__bf16)(acc[2][j] + bj[j]);
      v[3] = (__bf16)(acc[3][j] + bj[j]);
      *(bf16x4*)&Vtw[((size_t)bh * HD + d0 + j) * T_SEQ + tp] = v;
    }
  }
}

// ---------------------------------------------------------------------------
// Kernel 2: causal flash attention, bf16 MFMA (16x16x32).
// grid = (64 qtiles reversed, 24 bh), 256 threads = 4 independent waves.
// Wave w owns 16 q rows (qw = qt*64 + 16w). Computes St = K.Q^T (C-layout:
// row=s, col=q -> softmax state is per-lane scalar), then Ot = V^T.Pt.
// Pt goes C-layout -> A-layout via per-wave-private LDS (no __syncthreads).
// ---------------------------------------------------------------------------
__global__ __launch_bounds__(256) void attn_kernel(
    const __bf16* __restrict__ Q, const __bf16* __restrict__ K,
    const __bf16* __restrict__ Vt, float* __restrict__ O) {
  __shared__ __bf16 Pl[4][16][72];   // [wave][q-col][s], pad 72 vs 64

  const int t    = threadIdx.x;
  const int wv   = t >> 6;
  const int lane = t & 63;
  const int g2   = lane >> 4;        // 0..3
  const int c    = lane & 15;        // 0..15
  const int qt   = (int)gridDim.x - 1 - (int)blockIdx.x;  // big tiles first
  const int bh   = blockIdx.y;
  const int qw   = qt * 64 + wv * 16;

  const __bf16* Qb = Q  + (size_t)bh * T_SEQ * HD;
  const __bf16* Kb = K  + (size_t)bh * T_SEQ * HD;
  const __bf16* Vb = Vt + (size_t)bh * HD * T_SEQ;

  // Q^T B-fragments for this wave's 16 q rows: lane holds Q[qw+c][ds*32+8*g2..+7]
  bf16x8 qf[2];
  qf[0] = *(const bf16x8*)&Qb[(size_t)(qw + c) * HD +      (g2 << 3)];
  qf[1] = *(const bf16x8*)&Qb[(size_t)(qw + c) * HD + 32 + (g2 << 3)];

  f32x4 ot[4];
#pragma unroll
  for (int mt = 0; mt < 4; ++mt) ot[mt] = (f32x4){0.f, 0.f, 0.f, 0.f};
  float m_i = -INFINITY, l_i = 0.f;

  __bf16* plw = &Pl[wv][c][0];

  for (int kt = 0; kt <= qt; ++kt) {
    // ---- St = K . Q^T  (4 s-tiles of 16, K over D=64 in 2 steps) ----
    f32x4 S[4];
#pragma unroll
    for (int st = 0; st < 4; ++st) S[st] = (f32x4){0.f, 0.f, 0.f, 0.f};
    const __bf16* kb = Kb + (size_t)(kt * 64 + c) * HD + (g2 << 3);
#pragma unroll
    for (int ds = 0; ds < 2; ++ds) {
#pragma unroll
      for (int st = 0; st < 4; ++st) {
        bf16x8 kf = *(const bf16x8*)&kb[st * 16 * HD + ds * 32];
        S[st] = __builtin_amdgcn_mfma_f32_16x16x32_bf16(kf, qf[ds], S[st], 0, 0, 0);
      }
    }

    // ---- causal mask (diagonal tile only; wave-uniform branch) ----
    if (kt == qt) {
      const int qloc = (wv << 4) + c;
#pragma unroll
      for (int st = 0; st < 4; ++st)
#pragma unroll
        for (int r = 0; r < 4; ++r)
          if ((st << 4) + (g2 << 2) + r > qloc) S[st][r] = -INFINITY;
    }

    // ---- online softmax (per-lane state: column q = qw + c) ----
    float tmax = -INFINITY;
#pragma unroll
    for (int st = 0; st < 4; ++st)
#pragma unroll
      for (int r = 0; r < 4; ++r) tmax = fmaxf(tmax, S[st][r]);
    tmax = fmaxf(tmax, __shfl_xor(tmax, 16));
    tmax = fmaxf(tmax, __shfl_xor(tmax, 32));
    float m_new = fmaxf(m_i, tmax);
    float alpha = __expf(m_i - m_new);
    float psum = 0.f;
#pragma unroll
    for (int st = 0; st < 4; ++st)
#pragma unroll
      for (int r = 0; r < 4; ++r) {
        S[st][r] = __expf(S[st][r] - m_new);
        psum += S[st][r];
      }
    psum += __shfl_xor(psum, 16);
    psum += __shfl_xor(psum, 32);
    l_i = l_i * alpha + psum;
    m_i = m_new;
#pragma unroll
    for (int mt = 0; mt < 4; ++mt)
#pragma unroll
      for (int r = 0; r < 4; ++r) ot[mt][r] *= alpha;

    // ---- Pt: C-layout -> LDS [c][s] (bf16), then read A... B-fragments ----
#pragma unroll
    for (int st = 0; st < 4; ++st) {
      bf16x2 p0; p0[0] = (__bf16)S[st][0]; p0[1] = (__bf16)S[st][1];
      bf16x2 p1; p1[0] = (__bf16)S[st][2]; p1[1] = (__bf16)S[st][3];
      *(bf16x2*)&plw[(st << 4) + (g2 << 2)]     = p0;
      *(bf16x2*)&plw[(st << 4) + (g2 << 2) + 2] = p1;
    }
    asm volatile("s_waitcnt lgkmcnt(0)" ::: "memory");  // wave-local WAR/RAW fence
    bf16x8 pf0 = *(const bf16x8*)&plw[     (g2 << 3)];
    bf16x8 pf1 = *(const bf16x8*)&plw[32 + (g2 << 3)];

    // ---- Ot += V^T . Pt  (4 d-tiles, K over s=64 in 2 steps) ----
    const __bf16* vb = Vb + (size_t)c * T_SEQ + kt * 64 + (g2 << 3);
#pragma unroll
    for (int mt = 0; mt < 4; ++mt) {
      bf16x8 vf0 = *(const bf16x8*)&vb[(size_t)(mt * 16) * T_SEQ];
      bf16x8 vf1 = *(const bf16x8*)&vb[(size_t)(mt * 16) * T_SEQ + 32];
      ot[mt] = __builtin_amdgcn_mfma_f32_16x16x32_bf16(vf0, pf0, ot[mt], 0, 0, 0);
      ot[mt] = __builtin_amdgcn_mfma_f32_16x16x32_bf16(vf1, pf1, ot[mt], 0, 0, 0);
    }
  }

  // ---- epilogue: normalize, scatter to O[B*T][C] ----
  const float inv = 1.f / l_i;
  const int b = bh / NH, hh = bh % NH;
  float* orow = O + ((size_t)(b * T_SEQ + qw + c)) * CDIM + hh * HD;
#pragma unroll
  for (int mt = 0; mt < 4; ++mt) {
    f32x4 v = ot[mt];
    v[0] *= inv; v[1] *= inv; v[2] *= inv; v[3] *= inv;
    *(f32x4*)&orow[mt * 16 + (g2 << 2)] = v;
  }
}

// ---------------------------------------------------------------------------
// Kernel 3: out = O @ W_proj + b_proj (fp32 SGEMM).
// grid = (CDIM/64 = 12, MROWS/64 = 128)
// ---------------------------------------------------------------------------
__global__ __launch_bounds__(256) void proj_gemm_kernel(
    const float* __restrict__ A, const float* __restrict__ W,
    const float* __restrict__ bias, float* __restrict__ out) {
  __shared__ float As[16][64];
  __shared__ float Bs[16][68];

  const int t  = threadIdx.x;
  const int m0 = blockIdx.y * 64;
  const int n0 = blockIdx.x * 64;
  const int tx = t & 15, ty = t >> 4;
  const int arow = t >> 2, ak = (t & 3) << 2;
  const int brow = t >> 4, bcol = (t & 15) << 2;

  float acc[4][4] = {};

  for (int k0 = 0; k0 < CDIM; k0 += 16) {
    float4 av = *(const float4*)&A[(size_t)(m0 + arow) * CDIM + k0 + ak];
    float4 bv = *(const float4*)&W[(size_t)(k0 + brow) * CDIM + n0 + bcol];
    __syncthreads();
    As[ak + 0][arow] = av.x; As[ak + 1][arow] = av.y;
    As[ak + 2][arow] = av.z; As[ak + 3][arow] = av.w;
    *(float4*)&Bs[brow][bcol] = bv;
    __syncthreads();
#pragma unroll
    for (int kk = 0; kk < 16; ++kk) {
      float4 a = *(const float4*)&As[kk][ty << 2];
      float4 b = *(const float4*)&Bs[kk][tx << 2];
      float ar[4] = {a.x, a.y, a.z, a.w};
      float br[4] = {b.x, b.y, b.z, b.w};
#pragma unroll
      for (int i = 0; i < 4; ++i)
#pragma unroll
        for (int j = 0; j < 4; ++j) acc[i][j] = fmaf(ar[i], br[j], acc[i][j]);
    }
  }

  float4 bb = *(const float4*)&bias[n0 + (tx << 2)];
#pragma unroll
  for (int i = 0; i < 4; ++i) {
    int m = m0 + (ty << 2) + i;
    float4 v;
    v.x = acc[i][0] + bb.x; v.y = acc[i][1] + bb.y;
    v.z = acc[i][2] + bb.z; v.w = acc[i][3] + bb.w;
    *(float4*)&out[(size_t)m * CDIM + n0 + (tx << 2)] = v;
  }
}

// ---------------------------------------------------------------------------
extern "C" void kernel_launch(void* const* d_in, const int* in_sizes, int n_in,
                              void* d_out, int out_size, void* d_ws, size_t ws_size,
                              hipStream_t stream) {
  (void)in_sizes; (void)n_in; (void)out_size; (void)ws_size;
  const float* x      = (const float*)d_in[0];
  const float* W_qkv  = (const float*)d_in[1];
  const float* b_qkv  = (const float*)d_in[2];
  const float* W_proj = (const float*)d_in[3];
  const float* b_proj = (const float*)d_in[4];
  float* out = (float*)d_out;

  __bf16* Qw  = (__bf16*)d_ws;
  __bf16* Kw  = Qw + QKV_ELEMS;
  __bf16* Vtw = Kw + QKV_ELEMS;
  float*  Ow  = (float*)(Vtw + QKV_ELEMS);   // 37.7 MB offset, 16B-aligned

  // 1) QKV projection (+bias) -> bf16 Q/K [bh][T][64], Vt [bh][64][T]
  qkv_gemm_kernel<<<dim3(N3C / 64, MROWS / 64), 256, 0, stream>>>(
      x, W_qkv, b_qkv, Qw, Kw, Vtw);

  // 2) Causal flash attention (bf16 MFMA) -> O f32 [B*T][C]
  attn_kernel<<<dim3(T_SEQ / 64, HEADS_TOTAL), 256, 0, stream>>>(
      Qw, Kw, Vtw, Ow);

  // 3) Output projection (+bias), fp32
  proj_gemm_kernel<<<dim3(CDIM / 64, MROWS / 64), 256, 0, stream>>>(
      Ow, W_proj, b_proj, out);
}

// Round 3
// 769.687 us; speedup vs baseline: 2.7980x; 1.5755x over previous
//
#include <hip/hip_runtime.h>
#include <math.h>

// Problem constants
#define T_SEQ 4096
#define CDIM  768
#define NH    12
#define HD    64
#define BATCH 2
#define MROWS (BATCH * T_SEQ)   // 8192
#define N3C   (3 * CDIM)        // 2304
#define HEADS_TOTAL (BATCH * NH)                       // 24
#define QKV_ELEMS   ((size_t)HEADS_TOTAL * T_SEQ * HD) // 6,291,456

typedef __bf16 bf16x8 __attribute__((ext_vector_type(8)));
typedef __bf16 bf16x4 __attribute__((ext_vector_type(4)));
typedef __bf16 bf16x2 __attribute__((ext_vector_type(2)));
typedef float  f32x4  __attribute__((ext_vector_type(4)));

// ---------------------------------------------------------------------------
// Kernel 1: qkv = x @ W_qkv + b_qkv  (fp32 SGEMM), epilogue converts to bf16
// and scatters: Q (x0.125) / K -> [bh][T][64], V -> transposed [bh][64][T].
// grid = (36, 128), 256 threads.  (unchanged from R2 — validated)
// ---------------------------------------------------------------------------
__global__ __launch_bounds__(256) void qkv_gemm_kernel(
    const float* __restrict__ x, const float* __restrict__ W,
    const float* __restrict__ bias, __bf16* __restrict__ Qw,
    __bf16* __restrict__ Kw, __bf16* __restrict__ Vtw) {
  __shared__ float As[16][64];
  __shared__ float Bs[16][68];

  const int t  = threadIdx.x;
  const int m0 = blockIdx.y * 64;
  const int n0 = blockIdx.x * 64;
  const int tx = t & 15, ty = t >> 4;
  const int arow = t >> 2, ak = (t & 3) << 2;
  const int brow = t >> 4, bcol = (t & 15) << 2;

  float acc[4][4] = {};

  for (int k0 = 0; k0 < CDIM; k0 += 16) {
    float4 av = *(const float4*)&x[(size_t)(m0 + arow) * CDIM + k0 + ak];
    float4 bv = *(const float4*)&W[(size_t)(k0 + brow) * N3C + n0 + bcol];
    __syncthreads();
    As[ak + 0][arow] = av.x; As[ak + 1][arow] = av.y;
    As[ak + 2][arow] = av.z; As[ak + 3][arow] = av.w;
    *(float4*)&Bs[brow][bcol] = bv;
    __syncthreads();
#pragma unroll
    for (int kk = 0; kk < 16; ++kk) {
      float4 a = *(const float4*)&As[kk][ty << 2];
      float4 b = *(const float4*)&Bs[kk][tx << 2];
      float ar[4] = {a.x, a.y, a.z, a.w};
      float br[4] = {b.x, b.y, b.z, b.w};
#pragma unroll
      for (int i = 0; i < 4; ++i)
#pragma unroll
        for (int j = 0; j < 4; ++j) acc[i][j] = fmaf(ar[i], br[j], acc[i][j]);
    }
  }

  const int sel = n0 / CDIM;
  const int hh  = (n0 % CDIM) / HD;
  const int d0  = tx << 2;
  float4 bb = *(const float4*)&bias[n0 + d0];
  float bj[4] = {bb.x, bb.y, bb.z, bb.w};

  if (sel < 2) {
    __bf16* dst = (sel == 0) ? Qw : Kw;
    const float scl = (sel == 0) ? 0.125f : 1.0f;   // fold 1/sqrt(D) into Q
#pragma unroll
    for (int i = 0; i < 4; ++i) {
      int m = m0 + (ty << 2) + i;
      int b = m >> 12, tp = m & 4095;
      int bh = b * NH + hh;
      bf16x4 v;
      v[0] = (__bf16)((acc[i][0] + bj[0]) * scl);
      v[1] = (__bf16)((acc[i][1] + bj[1]) * scl);
      v[2] = (__bf16)((acc[i][2] + bj[2]) * scl);
      v[3] = (__bf16)((acc[i][3] + bj[3]) * scl);
      *(bf16x4*)&dst[((size_t)bh * T_SEQ + tp) * HD + d0] = v;
    }
  } else {
    int m = m0 + (ty << 2);
    int b = m >> 12, tp = m & 4095;
    int bh = b * NH + hh;
#pragma unroll
    for (int j = 0; j < 4; ++j) {
      bf16x4 v;
      v[0] = (__bf16)(acc[0][j] + bj[j]);
      v[1] = (__bf16)(acc[1][j] + bj[j]);
      v[2] = (__bf16)(acc[2][j] + bj[j]);
      v[3] = (__bf16)(acc[3][j] + bj[j]);
      *(bf16x4*)&Vtw[((size_t)bh * HD + d0 + j) * T_SEQ + tp] = v;
    }
  }
}

// ---------------------------------------------------------------------------
// Kernel 2: causal flash attention, bf16 MFMA, LDS-staged K/V double buffer.
// grid = (32 tile-PAIRS, 24 bh), 256 threads = 4 waves.
// Block pi processes q-tiles {pi, 63-pi}: (pi+1)+(64-pi) = 65 iterations for
// every block -> perfect balance, 768 blocks = 3/CU.
// Per iteration: prefetch next K/V tile (coalesced 1KB/instr global loads into
// regs), compute S = K.Q^T / softmax / PV from current LDS buffers, ds_write
// prefetched tile into other buffer, one __syncthreads.
// LDS rows padded to 72 bf16 (144B): all b128 reads/writes are 8 lanes per
// bank-quad = conflict-free optimum.
// ---------------------------------------------------------------------------
struct Stage { bf16x8 k0, k1, v0, v1; };

__device__ __forceinline__ void issue_stage(const __bf16* __restrict__ Kb,
                                            const __bf16* __restrict__ Vb,
                                            int kt, int wv, int lane, Stage& sg) {
  const int r8 = lane >> 3;               // 0..7
  const int cc = (lane & 7) << 3;         // 16B col, elements
  const int row0 = (wv << 4) + r8;        // wave's 16 rows of the 64-row tile
  const int row1 = row0 + 8;
  sg.k0 = *(const bf16x8*)&Kb[(size_t)(kt * 64 + row0) * HD + cc];
  sg.k1 = *(const bf16x8*)&Kb[(size_t)(kt * 64 + row1) * HD + cc];
  sg.v0 = *(const bf16x8*)&Vb[(size_t)row0 * T_SEQ + kt * 64 + cc];
  sg.v1 = *(const bf16x8*)&Vb[(size_t)row1 * T_SEQ + kt * 64 + cc];
}

__device__ __forceinline__ void write_stage(__bf16 (*KT)[72], __bf16 (*VT)[72],
                                            int wv, int lane, const Stage& sg) {
  const int r8 = lane >> 3;
  const int cc = (lane & 7) << 3;
  const int row0 = (wv << 4) + r8;
  const int row1 = row0 + 8;
  *(bf16x8*)&KT[row0][cc] = sg.k0;
  *(bf16x8*)&KT[row1][cc] = sg.k1;
  *(bf16x8*)&VT[row0][cc] = sg.v0;
  *(bf16x8*)&VT[row1][cc] = sg.v1;
}

__global__ __launch_bounds__(256) void attn_kernel(
    const __bf16* __restrict__ Q, const __bf16* __restrict__ K,
    const __bf16* __restrict__ Vt, float* __restrict__ O) {
  __shared__ __align__(16) __bf16 KT[2][64][72];   // [buf][s][d], 18KB
  __shared__ __align__(16) __bf16 VT[2][64][72];   // [buf][d][s], 18KB
  __shared__ __align__(16) __bf16 Pl[4][16][72];   // per-wave P, 9KB

  const int t    = threadIdx.x;
  const int wv   = t >> 6;
  const int lane = t & 63;
  const int g2   = lane >> 4;        // 0..3
  const int c    = lane & 15;        // 0..15
  const int pi   = blockIdx.x;       // 0..31
  const int bh   = blockIdx.y;

  const __bf16* Qb = Q  + (size_t)bh * T_SEQ * HD;
  const __bf16* Kb = K  + (size_t)bh * T_SEQ * HD;
  const __bf16* Vb = Vt + (size_t)bh * HD * T_SEQ;
  __bf16* plw = &Pl[wv][c][0];

  const int b  = bh / NH, hh = bh % NH;

#pragma unroll 1
  for (int half = 0; half < 2; ++half) {
    const int qt = half ? (63 - pi) : pi;
    const int qw = qt * 64 + wv * 16;

    // Q^T B-fragments: lane holds Q[qw+c][ds*32 + 8*g2 .. +7]
    bf16x8 qf0 = *(const bf16x8*)&Qb[(size_t)(qw + c) * HD +      (g2 << 3)];
    bf16x8 qf1 = *(const bf16x8*)&Qb[(size_t)(qw + c) * HD + 32 + (g2 << 3)];

    f32x4 ot[4];
#pragma unroll
    for (int mt = 0; mt < 4; ++mt) ot[mt] = (f32x4){0.f, 0.f, 0.f, 0.f};
    float m_i = -INFINITY, l_i = 0.f;

    Stage sg;
    issue_stage(Kb, Vb, 0, wv, lane, sg);
    write_stage(KT[0], VT[0], wv, lane, sg);
    __syncthreads();

#pragma unroll 1
    for (int kt = 0; kt <= qt; ++kt) {
      const int cur = kt & 1;
      if (kt < qt) issue_stage(Kb, Vb, kt + 1, wv, lane, sg);  // async prefetch

      // ---- St = K . Q^T  (4 s-tiles of 16, K over D=64 in 2 steps) ----
      f32x4 S[4];
#pragma unroll
      for (int st = 0; st < 4; ++st) S[st] = (f32x4){0.f, 0.f, 0.f, 0.f};
#pragma unroll
      for (int st = 0; st < 4; ++st) {
        bf16x8 kfa = *(const bf16x8*)&KT[cur][st * 16 + c][(g2 << 3)];
        bf16x8 kfb = *(const bf16x8*)&KT[cur][st * 16 + c][(g2 << 3) + 32];
        S[st] = __builtin_amdgcn_mfma_f32_16x16x32_bf16(kfa, qf0, S[st], 0, 0, 0);
        S[st] = __builtin_amdgcn_mfma_f32_16x16x32_bf16(kfb, qf1, S[st], 0, 0, 0);
      }

      // ---- causal mask (diagonal tile only) ----
      if (kt == qt) {
        const int qloc = (wv << 4) + c;
#pragma unroll
        for (int st = 0; st < 4; ++st)
#pragma unroll
          for (int r = 0; r < 4; ++r)
            if ((st << 4) + (g2 << 2) + r > qloc) S[st][r] = -INFINITY;
      }

      // ---- online softmax (per-lane state: column q = qw + c) ----
      float tmax = -INFINITY;
#pragma unroll
      for (int st = 0; st < 4; ++st)
#pragma unroll
        for (int r = 0; r < 4; ++r) tmax = fmaxf(tmax, S[st][r]);
      tmax = fmaxf(tmax, __shfl_xor(tmax, 16));
      tmax = fmaxf(tmax, __shfl_xor(tmax, 32));
      float m_new = fmaxf(m_i, tmax);
      float alpha = __expf(m_i - m_new);
      float psum = 0.f;
#pragma unroll
      for (int st = 0; st < 4; ++st)
#pragma unroll
        for (int r = 0; r < 4; ++r) {
          S[st][r] = __expf(S[st][r] - m_new);
          psum += S[st][r];
        }
      psum += __shfl_xor(psum, 16);
      psum += __shfl_xor(psum, 32);
      l_i = l_i * alpha + psum;
      m_i = m_new;
#pragma unroll
      for (int mt = 0; mt < 4; ++mt)
#pragma unroll
        for (int r = 0; r < 4; ++r) ot[mt][r] *= alpha;

      // ---- Pt: C-layout -> per-wave LDS -> A/B fragment layout ----
#pragma unroll
      for (int st = 0; st < 4; ++st) {
        bf16x2 p0; p0[0] = (__bf16)S[st][0]; p0[1] = (__bf16)S[st][1];
        bf16x2 p1; p1[0] = (__bf16)S[st][2]; p1[1] = (__bf16)S[st][3];
        *(bf16x2*)&plw[(st << 4) + (g2 << 2)]     = p0;
        *(bf16x2*)&plw[(st << 4) + (g2 << 2) + 2] = p1;
      }
      asm volatile("s_waitcnt lgkmcnt(0)" ::: "memory");  // wave-local fence
      bf16x8 pf0 = *(const bf16x8*)&plw[     (g2 << 3)];
      bf16x8 pf1 = *(const bf16x8*)&plw[32 + (g2 << 3)];

      // ---- Ot += V^T . Pt  (4 d-tiles, K over s=64 in 2 steps) ----
#pragma unroll
      for (int mt = 0; mt < 4; ++mt) {
        bf16x8 vf0 = *(const bf16x8*)&VT[cur][mt * 16 + c][(g2 << 3)];
        bf16x8 vf1 = *(const bf16x8*)&VT[cur][mt * 16 + c][(g2 << 3) + 32];
        ot[mt] = __builtin_amdgcn_mfma_f32_16x16x32_bf16(vf0, pf0, ot[mt], 0, 0, 0);
        ot[mt] = __builtin_amdgcn_mfma_f32_16x16x32_bf16(vf1, pf1, ot[mt], 0, 0, 0);
      }

      if (kt < qt) write_stage(KT[cur ^ 1], VT[cur ^ 1], wv, lane, sg);
      __syncthreads();
    }

    // ---- epilogue: normalize, scatter to O[B*T][C] ----
    const float inv = 1.f / l_i;
    float* orow = O + ((size_t)(b * T_SEQ + qw + c)) * CDIM + hh * HD;
#pragma unroll
    for (int mt = 0; mt < 4; ++mt) {
      f32x4 v = ot[mt];
      v[0] *= inv; v[1] *= inv; v[2] *= inv; v[3] *= inv;
      *(f32x4*)&orow[mt * 16 + (g2 << 2)] = v;
    }
  }
}

// ---------------------------------------------------------------------------
// Kernel 3: out = O @ W_proj + b_proj (fp32 SGEMM). grid = (12, 128).
// ---------------------------------------------------------------------------
__global__ __launch_bounds__(256) void proj_gemm_kernel(
    const float* __restrict__ A, const float* __restrict__ W,
    const float* __restrict__ bias, float* __restrict__ out) {
  __shared__ float As[16][64];
  __shared__ float Bs[16][68];

  const int t  = threadIdx.x;
  const int m0 = blockIdx.y * 64;
  const int n0 = blockIdx.x * 64;
  const int tx = t & 15, ty = t >> 4;
  const int arow = t >> 2, ak = (t & 3) << 2;
  const int brow = t >> 4, bcol = (t & 15) << 2;

  float acc[4][4] = {};

  for (int k0 = 0; k0 < CDIM; k0 += 16) {
    float4 av = *(const float4*)&A[(size_t)(m0 + arow) * CDIM + k0 + ak];
    float4 bv = *(const float4*)&W[(size_t)(k0 + brow) * CDIM + n0 + bcol];
    __syncthreads();
    As[ak + 0][arow] = av.x; As[ak + 1][arow] = av.y;
    As[ak + 2][arow] = av.z; As[ak + 3][arow] = av.w;
    *(float4*)&Bs[brow][bcol] = bv;
    __syncthreads();
#pragma unroll
    for (int kk = 0; kk < 16; ++kk) {
      float4 a = *(const float4*)&As[kk][ty << 2];
      float4 b = *(const float4*)&Bs[kk][tx << 2];
      float ar[4] = {a.x, a.y, a.z, a.w};
      float br[4] = {b.x, b.y, b.z, b.w};
#pragma unroll
      for (int i = 0; i < 4; ++i)
#pragma unroll
        for (int j = 0; j < 4; ++j) acc[i][j] = fmaf(ar[i], br[j], acc[i][j]);
    }
  }

  float4 bb = *(const float4*)&bias[n0 + (tx << 2)];
#pragma unroll
  for (int i = 0; i < 4; ++i) {
    int m = m0 + (ty << 2) + i;
    float4 v;
    v.x = acc[i][0] + bb.x; v.y = acc[i][1] + bb.y;
    v.z = acc[i][2] + bb.z; v.w = acc[i][3] + bb.w;
    *(float4*)&out[(size_t)m * CDIM + n0 + (tx << 2)] = v;
  }
}

// ---------------------------------------------------------------------------
extern "C" void kernel_launch(void* const* d_in, const int* in_sizes, int n_in,
                              void* d_out, int out_size, void* d_ws, size_t ws_size,
                              hipStream_t stream) {
  (void)in_sizes; (void)n_in; (void)out_size; (void)ws_size;
  const float* x      = (const float*)d_in[0];
  const float* W_qkv  = (const float*)d_in[1];
  const float* b_qkv  = (const float*)d_in[2];
  const float* W_proj = (const float*)d_in[3];
  const float* b_proj = (const float*)d_in[4];
  float* out = (float*)d_out;

  __bf16* Qw  = (__bf16*)d_ws;
  __bf16* Kw  = Qw + QKV_ELEMS;
  __bf16* Vtw = Kw + QKV_ELEMS;
  float*  Ow  = (float*)(Vtw + QKV_ELEMS);

  qkv_gemm_kernel<<<dim3(N3C / 64, MROWS / 64), 256, 0, stream>>>(
      x, W_qkv, b_qkv, Qw, Kw, Vtw);

  // paired causal tiles: block pi does qt=pi and qt=63-pi (65 iters each)
  attn_kernel<<<dim3(32, HEADS_TOTAL), 256, 0, stream>>>(Qw, Kw, Vtw, Ow);

  proj_gemm_kernel<<<dim3(CDIM / 64, MROWS / 64), 256, 0, stream>>>(
      Ow, W_proj, b_proj, out);
}

// Round 4
// 276.619 us; speedup vs baseline: 7.7855x; 2.7825x over previous
//
#include <hip/hip_runtime.h>
#include <math.h>

// Problem constants
#define T_SEQ 4096
#define CDIM  768
#define NH    12
#define HD    64
#define BATCH 2
#define MROWS (BATCH * T_SEQ)   // 8192
#define N3C   (3 * CDIM)        // 2304
#define HEADS_TOTAL (BATCH * NH)                       // 24
#define QKV_ELEMS   ((size_t)HEADS_TOTAL * T_SEQ * HD) // 6,291,456

typedef __bf16 bf16x8 __attribute__((ext_vector_type(8)));
typedef __bf16 bf16x4 __attribute__((ext_vector_type(4)));
typedef __bf16 bf16x2 __attribute__((ext_vector_type(2)));
typedef float  f32x4  __attribute__((ext_vector_type(4)));

typedef __attribute__((address_space(1))) const void as1_cvoid;
typedef __attribute__((address_space(3))) void as3_void;

// async global->LDS, 16B per lane; LDS dest = wave-uniform base + lane*16
__device__ __forceinline__ void gl16(const void* g, void* l) {
  __builtin_amdgcn_global_load_lds((as1_cvoid*)g, (as3_void*)l, 16, 0, 0);
}

// ---------------------------------------------------------------------------
// Prep kernels: fp32 -> bf16 cast (x) and transpose-cast (weights).
// ---------------------------------------------------------------------------
__global__ __launch_bounds__(256) void cast_x_kernel(
    const float* __restrict__ x, __bf16* __restrict__ xb) {
  int i = (blockIdx.x * 256 + threadIdx.x) * 8;
  float4 a = *(const float4*)&x[i];
  float4 b = *(const float4*)&x[i + 4];
  bf16x8 o;
  o[0] = (__bf16)a.x; o[1] = (__bf16)a.y; o[2] = (__bf16)a.z; o[3] = (__bf16)a.w;
  o[4] = (__bf16)b.x; o[5] = (__bf16)b.y; o[6] = (__bf16)b.z; o[7] = (__bf16)b.w;
  *(bf16x8*)&xb[i] = o;
}

// W [K][N] fp32 -> Wt [N][K] bf16, 64x64 LDS tiles.
__global__ __launch_bounds__(256) void tcast_kernel(
    const float* __restrict__ W, __bf16* __restrict__ Wt, int K, int N) {
  __shared__ float tile[64][65];
  const int t  = threadIdx.x;
  const int k0 = blockIdx.y * 64, n0 = blockIdx.x * 64;
  const int r  = t >> 4, c4 = (t & 15) << 2;
#pragma unroll
  for (int i = 0; i < 4; ++i) {
    float4 v = *(const float4*)&W[(size_t)(k0 + r + i * 16) * N + n0 + c4];
    tile[r + i * 16][c4 + 0] = v.x; tile[r + i * 16][c4 + 1] = v.y;
    tile[r + i * 16][c4 + 2] = v.z; tile[r + i * 16][c4 + 3] = v.w;
  }
  __syncthreads();
#pragma unroll
  for (int i = 0; i < 4; ++i) {
    int nr = r + i * 16;
    bf16x4 o;
    o[0] = (__bf16)tile[c4 + 0][nr]; o[1] = (__bf16)tile[c4 + 1][nr];
    o[2] = (__bf16)tile[c4 + 2][nr]; o[3] = (__bf16)tile[c4 + 3][nr];
    *(bf16x4*)&Wt[(size_t)(n0 + nr) * K + k0 + c4] = o;
  }
}

// ---------------------------------------------------------------------------
// m97-style bf16 MFMA GEMM main loop: C[128x128] = A[128xK] . Bt[128xK]^T
// (both operands row-major-over-K, K=CDIM=768, BK=32). 256 thr = 4 waves,
// wave quadrant (mw,nw), 4x4 16x16x32 accumulators. global_load_lds staging.
// ---------------------------------------------------------------------------
__device__ __forceinline__ void mm_loop(const __bf16* __restrict__ A,
                                        const __bf16* __restrict__ Bt,
                                        int m0, int n0, __bf16* smem,
                                        f32x4 acc[4][4]) {
  const int t = threadIdx.x, wv = t >> 6, lane = t & 63;
  const int g2 = lane >> 4, c = lane & 15;
  __bf16* At = smem;          // [128][32]
  __bf16* Bs = smem + 4096;   // [128][32]
  const int ch0 = wv * 64 + lane;      // chunk = m*4 + kc
  const int ch1 = 256 + ch0;
  const __bf16* gA0 = A  + (size_t)(m0 + (ch0 >> 2)) * CDIM + ((ch0 & 3) << 3);
  const __bf16* gA1 = A  + (size_t)(m0 + (ch1 >> 2)) * CDIM + ((ch1 & 3) << 3);
  const __bf16* gB0 = Bt + (size_t)(n0 + (ch0 >> 2)) * CDIM + ((ch0 & 3) << 3);
  const __bf16* gB1 = Bt + (size_t)(n0 + (ch1 >> 2)) * CDIM + ((ch1 & 3) << 3);
  __bf16* lA0 = At + (size_t)(wv * 64) * 8;          // wave-uniform LDS bases
  __bf16* lA1 = At + (size_t)(256 + wv * 64) * 8;
  __bf16* lB0 = Bs + (size_t)(wv * 64) * 8;
  __bf16* lB1 = Bs + (size_t)(256 + wv * 64) * 8;
  const int mw = (wv & 1) << 6, nw = (wv >> 1) << 6;

  for (int kk = 0; kk < CDIM / 32; ++kk) {
    __syncthreads();                          // prev tile fully consumed
    gl16(gA0, lA0); gl16(gA1, lA1);
    gl16(gB0, lB0); gl16(gB1, lB1);
    gA0 += 32; gA1 += 32; gB0 += 32; gB1 += 32;
    __syncthreads();                          // vmcnt drained -> tile ready
    bf16x8 af[4], bfr[4];
#pragma unroll
    for (int mq = 0; mq < 4; ++mq)
      af[mq] = *(const bf16x8*)&At[(size_t)(mw + mq * 16 + c) * 32 + (g2 << 3)];
#pragma unroll
    for (int nq = 0; nq < 4; ++nq)
      bfr[nq] = *(const bf16x8*)&Bs[(size_t)(nw + nq * 16 + c) * 32 + (g2 << 3)];
#pragma unroll
    for (int mq = 0; mq < 4; ++mq)
#pragma unroll
      for (int nq = 0; nq < 4; ++nq)
        acc[mq][nq] = __builtin_amdgcn_mfma_f32_16x16x32_bf16(
            af[mq], bfr[nq], acc[mq][nq], 0, 0, 0);
  }
  __syncthreads();   // smem free for epilogue reuse
}

// ---------------------------------------------------------------------------
// Kernel 1: qkv = xb @ Wqkvt^T + b  (bf16 MFMA), epilogue re-tiles via
// per-wave LDS: Q(x0.125)/K -> [bh][T][64] bf16, V -> [bh][64][T] bf16.
// grid = (2304/128=18, 8192/128=64). Each wave's 64 cols = one head exactly.
// ---------------------------------------------------------------------------
__global__ __launch_bounds__(256) void qkv_mm_kernel(
    const __bf16* __restrict__ xb, const __bf16* __restrict__ Wt,
    const float* __restrict__ bias, __bf16* __restrict__ Qw,
    __bf16* __restrict__ Kw, __bf16* __restrict__ Vtw) {
  __shared__ __align__(16) __bf16 smem[18432];   // staging 8K elems; epi 4x64x72
  f32x4 acc[4][4];
#pragma unroll
  for (int i = 0; i < 4; ++i)
#pragma unroll
    for (int j = 0; j < 4; ++j) acc[i][j] = (f32x4){0.f, 0.f, 0.f, 0.f};

  const int m0 = blockIdx.y * 128, n0 = blockIdx.x * 128;
  mm_loop(xb, Wt, m0, n0, smem, acc);

  const int t = threadIdx.x, wv = t >> 6, lane = t & 63;
  const int g2 = lane >> 4, c = lane & 15;
  const int sel = n0 / CDIM;                 // 18 blocks: 6 per Q/K/V
  const int nn0 = n0 - sel * CDIM;
  const int h   = (nn0 >> 6) + (wv >> 1);    // wave's head
  const int mbase = m0 + ((wv & 1) << 6);
  const int b = mbase >> 12, tp0 = mbase & 4095;
  const int bh = b * NH + h;
  __bf16* Ep = smem + wv * 4608;             // per-wave 64x72
  float bcol[4];
#pragma unroll
  for (int nq = 0; nq < 4; ++nq)
    bcol[nq] = bias[n0 + ((wv >> 1) << 6) + nq * 16 + c];

  const int r8 = lane >> 3, c8 = (lane & 7) << 3;
  if (sel < 2) {
    const float scl = (sel == 0) ? 0.125f : 1.0f;   // fold 1/sqrt(D) into Q
#pragma unroll
    for (int mq = 0; mq < 4; ++mq)
#pragma unroll
      for (int nq = 0; nq < 4; ++nq)
#pragma unroll
        for (int r = 0; r < 4; ++r)
          Ep[(size_t)(mq * 16 + (g2 << 2) + r) * 72 + nq * 16 + c] =
              (__bf16)((acc[mq][nq][r] + bcol[nq]) * scl);
    asm volatile("s_waitcnt lgkmcnt(0)" ::: "memory");  // wave-local fence
    __bf16* dst = (sel == 0) ? Qw : Kw;
#pragma unroll
    for (int p = 0; p < 8; ++p) {
      int row = p * 8 + r8;
      bf16x8 v = *(const bf16x8*)&Ep[(size_t)row * 72 + c8];
      *(bf16x8*)&dst[((size_t)bh * T_SEQ + tp0 + row) * HD + c8] = v;
    }
  } else {
    // V: store transposed into Ep -> contiguous-in-t reads
#pragma unroll
    for (int mq = 0; mq < 4; ++mq)
#pragma unroll
      for (int nq = 0; nq < 4; ++nq)
#pragma unroll
        for (int r = 0; r < 4; ++r)
          Ep[(size_t)(nq * 16 + c) * 72 + mq * 16 + (g2 << 2) + r] =
              (__bf16)(acc[mq][nq][r] + bcol[nq]);
    asm volatile("s_waitcnt lgkmcnt(0)" ::: "memory");
#pragma unroll
    for (int p = 0; p < 8; ++p) {
      int d = p * 8 + r8;
      bf16x8 v = *(const bf16x8*)&Ep[(size_t)d * 72 + c8];
      *(bf16x8*)&Vtw[((size_t)bh * HD + d) * T_SEQ + tp0 + c8] = v;
    }
  }
}

// ---------------------------------------------------------------------------
// Kernel 2: causal flash attention (R3-validated), now emits bf16 O.
// ---------------------------------------------------------------------------
struct Stage { bf16x8 k0, k1, v0, v1; };

__device__ __forceinline__ void issue_stage(const __bf16* __restrict__ Kb,
                                            const __bf16* __restrict__ Vb,
                                            int kt, int wv, int lane, Stage& sg) {
  const int r8 = lane >> 3;
  const int cc = (lane & 7) << 3;
  const int row0 = (wv << 4) + r8;
  const int row1 = row0 + 8;
  sg.k0 = *(const bf16x8*)&Kb[(size_t)(kt * 64 + row0) * HD + cc];
  sg.k1 = *(const bf16x8*)&Kb[(size_t)(kt * 64 + row1) * HD + cc];
  sg.v0 = *(const bf16x8*)&Vb[(size_t)row0 * T_SEQ + kt * 64 + cc];
  sg.v1 = *(const bf16x8*)&Vb[(size_t)row1 * T_SEQ + kt * 64 + cc];
}

__device__ __forceinline__ void write_stage(__bf16 (*KT)[72], __bf16 (*VT)[72],
                                            int wv, int lane, const Stage& sg) {
  const int r8 = lane >> 3;
  const int cc = (lane & 7) << 3;
  const int row0 = (wv << 4) + r8;
  const int row1 = row0 + 8;
  *(bf16x8*)&KT[row0][cc] = sg.k0;
  *(bf16x8*)&KT[row1][cc] = sg.k1;
  *(bf16x8*)&VT[row0][cc] = sg.v0;
  *(bf16x8*)&VT[row1][cc] = sg.v1;
}

__global__ __launch_bounds__(256) void attn_kernel(
    const __bf16* __restrict__ Q, const __bf16* __restrict__ K,
    const __bf16* __restrict__ Vt, __bf16* __restrict__ O) {
  __shared__ __align__(16) __bf16 KT[2][64][72];
  __shared__ __align__(16) __bf16 VT[2][64][72];
  __shared__ __align__(16) __bf16 Pl[4][16][72];

  const int t    = threadIdx.x;
  const int wv   = t >> 6;
  const int lane = t & 63;
  const int g2   = lane >> 4;
  const int c    = lane & 15;
  const int pi   = blockIdx.x;
  const int bh   = blockIdx.y;

  const __bf16* Qb = Q  + (size_t)bh * T_SEQ * HD;
  const __bf16* Kb = K  + (size_t)bh * T_SEQ * HD;
  const __bf16* Vb = Vt + (size_t)bh * HD * T_SEQ;
  __bf16* plw = &Pl[wv][c][0];

  const int b = bh / NH, hh = bh % NH;

#pragma unroll 1
  for (int half = 0; half < 2; ++half) {
    const int qt = half ? (63 - pi) : pi;
    const int qw = qt * 64 + wv * 16;

    bf16x8 qf0 = *(const bf16x8*)&Qb[(size_t)(qw + c) * HD +      (g2 << 3)];
    bf16x8 qf1 = *(const bf16x8*)&Qb[(size_t)(qw + c) * HD + 32 + (g2 << 3)];

    f32x4 ot[4];
#pragma unroll
    for (int mt = 0; mt < 4; ++mt) ot[mt] = (f32x4){0.f, 0.f, 0.f, 0.f};
    float m_i = -INFINITY, l_i = 0.f;

    Stage sg;
    issue_stage(Kb, Vb, 0, wv, lane, sg);
    write_stage(KT[0], VT[0], wv, lane, sg);
    __syncthreads();

#pragma unroll 1
    for (int kt = 0; kt <= qt; ++kt) {
      const int cur = kt & 1;
      if (kt < qt) issue_stage(Kb, Vb, kt + 1, wv, lane, sg);

      f32x4 S[4];
#pragma unroll
      for (int st = 0; st < 4; ++st) S[st] = (f32x4){0.f, 0.f, 0.f, 0.f};
#pragma unroll
      for (int st = 0; st < 4; ++st) {
        bf16x8 kfa = *(const bf16x8*)&KT[cur][st * 16 + c][(g2 << 3)];
        bf16x8 kfb = *(const bf16x8*)&KT[cur][st * 16 + c][(g2 << 3) + 32];
        S[st] = __builtin_amdgcn_mfma_f32_16x16x32_bf16(kfa, qf0, S[st], 0, 0, 0);
        S[st] = __builtin_amdgcn_mfma_f32_16x16x32_bf16(kfb, qf1, S[st], 0, 0, 0);
      }

      if (kt == qt) {
        const int qloc = (wv << 4) + c;
#pragma unroll
        for (int st = 0; st < 4; ++st)
#pragma unroll
          for (int r = 0; r < 4; ++r)
            if ((st << 4) + (g2 << 2) + r > qloc) S[st][r] = -INFINITY;
      }

      float tmax = -INFINITY;
#pragma unroll
      for (int st = 0; st < 4; ++st)
#pragma unroll
        for (int r = 0; r < 4; ++r) tmax = fmaxf(tmax, S[st][r]);
      tmax = fmaxf(tmax, __shfl_xor(tmax, 16));
      tmax = fmaxf(tmax, __shfl_xor(tmax, 32));
      float m_new = fmaxf(m_i, tmax);
      float alpha = __expf(m_i - m_new);
      float psum = 0.f;
#pragma unroll
      for (int st = 0; st < 4; ++st)
#pragma unroll
        for (int r = 0; r < 4; ++r) {
          S[st][r] = __expf(S[st][r] - m_new);
          psum += S[st][r];
        }
      psum += __shfl_xor(psum, 16);
      psum += __shfl_xor(psum, 32);
      l_i = l_i * alpha + psum;
      m_i = m_new;
#pragma unroll
      for (int mt = 0; mt < 4; ++mt)
#pragma unroll
        for (int r = 0; r < 4; ++r) ot[mt][r] *= alpha;

#pragma unroll
      for (int st = 0; st < 4; ++st) {
        bf16x2 p0; p0[0] = (__bf16)S[st][0]; p0[1] = (__bf16)S[st][1];
        bf16x2 p1; p1[0] = (__bf16)S[st][2]; p1[1] = (__bf16)S[st][3];
        *(bf16x2*)&plw[(st << 4) + (g2 << 2)]     = p0;
        *(bf16x2*)&plw[(st << 4) + (g2 << 2) + 2] = p1;
      }
      asm volatile("s_waitcnt lgkmcnt(0)" ::: "memory");
      bf16x8 pf0 = *(const bf16x8*)&plw[     (g2 << 3)];
      bf16x8 pf1 = *(const bf16x8*)&plw[32 + (g2 << 3)];

#pragma unroll
      for (int mt = 0; mt < 4; ++mt) {
        bf16x8 vf0 = *(const bf16x8*)&VT[cur][mt * 16 + c][(g2 << 3)];
        bf16x8 vf1 = *(const bf16x8*)&VT[cur][mt * 16 + c][(g2 << 3) + 32];
        ot[mt] = __builtin_amdgcn_mfma_f32_16x16x32_bf16(vf0, pf0, ot[mt], 0, 0, 0);
        ot[mt] = __builtin_amdgcn_mfma_f32_16x16x32_bf16(vf1, pf1, ot[mt], 0, 0, 0);
      }

      if (kt < qt) write_stage(KT[cur ^ 1], VT[cur ^ 1], wv, lane, sg);
      __syncthreads();
    }

    // epilogue: normalize, write bf16 O in [B*T][C] layout
    const float inv = 1.f / l_i;
    __bf16* orow = O + ((size_t)(b * T_SEQ + qw + c)) * CDIM + hh * HD;
#pragma unroll
    for (int mt = 0; mt < 4; ++mt) {
      bf16x4 v;
      v[0] = (__bf16)(ot[mt][0] * inv); v[1] = (__bf16)(ot[mt][1] * inv);
      v[2] = (__bf16)(ot[mt][2] * inv); v[3] = (__bf16)(ot[mt][3] * inv);
      *(bf16x4*)&orow[mt * 16 + (g2 << 2)] = v;
    }
  }
}

// ---------------------------------------------------------------------------
// Kernel 3: out = Ob @ Wprojt^T + b_proj (bf16 MFMA, fp32 out).
// grid = (768/128=6, 64).
// ---------------------------------------------------------------------------
__global__ __launch_bounds__(256) void proj_mm_kernel(
    const __bf16* __restrict__ Ob, const __bf16* __restrict__ Wt,
    const float* __restrict__ bias, float* __restrict__ out) {
  __shared__ __align__(16) __bf16 smem[8192];
  f32x4 acc[4][4];
#pragma unroll
  for (int i = 0; i < 4; ++i)
#pragma unroll
    for (int j = 0; j < 4; ++j) acc[i][j] = (f32x4){0.f, 0.f, 0.f, 0.f};

  const int m0 = blockIdx.y * 128, n0 = blockIdx.x * 128;
  mm_loop(Ob, Wt, m0, n0, smem, acc);

  const int t = threadIdx.x, wv = t >> 6, lane = t & 63;
  const int g2 = lane >> 4, c = lane & 15;
  const int mb = m0 + ((wv & 1) << 6), nb = n0 + ((wv >> 1) << 6);
  float bcol[4];
#pragma unroll
  for (int nq = 0; nq < 4; ++nq) bcol[nq] = bias[nb + nq * 16 + c];
#pragma unroll
  for (int mq = 0; mq < 4; ++mq)
#pragma unroll
    for (int nq = 0; nq < 4; ++nq)
#pragma unroll
      for (int r = 0; r < 4; ++r)
        out[(size_t)(mb + mq * 16 + (g2 << 2) + r) * CDIM + nb + nq * 16 + c] =
            acc[mq][nq][r] + bcol[nq];
}

// ---------------------------------------------------------------------------
extern "C" void kernel_launch(void* const* d_in, const int* in_sizes, int n_in,
                              void* d_out, int out_size, void* d_ws, size_t ws_size,
                              hipStream_t stream) {
  (void)in_sizes; (void)n_in; (void)out_size; (void)ws_size;
  const float* x      = (const float*)d_in[0];
  const float* W_qkv  = (const float*)d_in[1];
  const float* b_qkv  = (const float*)d_in[2];
  const float* W_proj = (const float*)d_in[3];
  const float* b_proj = (const float*)d_in[4];
  float* out = (float*)d_out;

  __bf16* Qw     = (__bf16*)d_ws;
  __bf16* Kw     = Qw  + QKV_ELEMS;
  __bf16* Vtw    = Kw  + QKV_ELEMS;
  __bf16* Ob     = Vtw + QKV_ELEMS;           // attn output, bf16 [B*T][C]
  __bf16* xb     = Ob  + QKV_ELEMS;           // x cast
  __bf16* Wqkvt  = xb  + QKV_ELEMS;           // [2304][768]
  __bf16* Wprojt = Wqkvt + (size_t)CDIM * N3C; // [768][768]

  // prep: casts + weight transposes
  cast_x_kernel<<<MROWS * CDIM / 2048, 256, 0, stream>>>(x, xb);
  tcast_kernel<<<dim3(N3C / 64, CDIM / 64), 256, 0, stream>>>(
      W_qkv, Wqkvt, CDIM, N3C);
  tcast_kernel<<<dim3(CDIM / 64, CDIM / 64), 256, 0, stream>>>(
      W_proj, Wprojt, CDIM, CDIM);

  // 1) QKV projection (bf16 MFMA) -> Q/K [bh][T][64], Vt [bh][64][T]
  qkv_mm_kernel<<<dim3(N3C / 128, MROWS / 128), 256, 0, stream>>>(
      xb, Wqkvt, b_qkv, Qw, Kw, Vtw);

  // 2) Causal flash attention -> Ob bf16 [B*T][C]
  attn_kernel<<<dim3(32, HEADS_TOTAL), 256, 0, stream>>>(Qw, Kw, Vtw, Ob);

  // 3) Output projection (bf16 MFMA, fp32 out)
  proj_mm_kernel<<<dim3(CDIM / 128, MROWS / 128), 256, 0, stream>>>(
      Ob, Wprojt, b_proj, out);
}